// Round 3
// baseline (555.155 us; speedup 1.0000x reference)
//
#include <hip/hip_runtime.h>
#include <float.h>

#define KNN   5
#define FEPS  1e-6f
#define NSAMP 10
#define MAXF  6000

__global__ __launch_bounds__(256) void otl_kernel(
    const float* __restrict__ verts,
    const int*   __restrict__ faces,
    const float* __restrict__ uarr,
    const float* __restrict__ varr,
    float* __restrict__ out,
    int F, int N)
{
    __shared__ float4 sc[MAXF];
    __shared__ float  wsum[4];

    // Build centroids into LDS (verts 48KB + faces 72KB are L2-resident;
    // 24 gather iterations per block, negligible vs the 6000-iter scan).
    for (int i = threadIdx.x; i < F; i += blockDim.x) {
        int i0 = faces[3*i], i1 = faces[3*i+1], i2 = faces[3*i+2];
        float cx = (verts[3*i0+0] + verts[3*i1+0] + verts[3*i2+0]) * (1.0f/3.0f);
        float cy = (verts[3*i0+1] + verts[3*i1+1] + verts[3*i2+1]) * (1.0f/3.0f);
        float cz = (verts[3*i0+2] + verts[3*i1+2] + verts[3*i2+2]) * (1.0f/3.0f);
        sc[i] = make_float4(cx, cy, cz, 0.0f);
    }
    __syncthreads();

    int tid = blockIdx.x * blockDim.x + threadIdx.x;
    float psum = 0.0f;

    if (tid < N) {
        int f = tid / NSAMP;
        float uu = uarr[tid], vv = varr[tid];
        if (uu + vv > 1.0f) { uu = 1.0f - uu; vv = 1.0f - vv; }
        float w0 = 1.0f - uu - vv;

        int i0 = faces[3*f], i1 = faces[3*f+1], i2 = faces[3*f+2];
        float px = verts[3*i0+0]*w0 + verts[3*i1+0]*uu + verts[3*i2+0]*vv;
        float py = verts[3*i0+1]*w0 + verts[3*i1+1]*uu + verts[3*i2+1]*vv;
        float pz = verts[3*i0+2]*w0 + verts[3*i1+2]*uu + verts[3*i2+2]*vv;

        // sorted top-5 (ascending distance); strict '<' + ascending j scan
        // reproduces top_k's smallest-index tie-break.
        float d0=FLT_MAX,d1=FLT_MAX,d2=FLT_MAX,d3=FLT_MAX,d4=FLT_MAX;
        int   j0=0,   j1=0,   j2=0,   j3=0,   j4=0;

        #pragma unroll 4
        for (int j = 0; j < F; ++j) {
            float4 c = sc[j];                      // wave-uniform LDS broadcast
            float dx = px - c.x, dy = py - c.y, dz = pz - c.z;
            float dist = fmaf(dx, dx, fmaf(dy, dy, dz*dz));
            if (dist < d4) {
                if (dist < d3) {
                    d4 = d3; j4 = j3;
                    if (dist < d2) {
                        d3 = d2; j3 = j2;
                        if (dist < d1) {
                            d2 = d1; j2 = j1;
                            if (dist < d0) { d1 = d0; j1 = j0; d0 = dist; j0 = j; }
                            else           { d1 = dist; j1 = j; }
                        } else { d2 = dist; j2 = j; }
                    } else { d3 = dist; j3 = j; }
                } else { d4 = dist; j4 = j; }
            }
        }

        int jj[KNN] = { j0, j1, j2, j3, j4 };
        #pragma unroll
        for (int k = 0; k < KNN; ++k) {
            int fj = jj[k];
            int a0 = faces[3*fj], a1 = faces[3*fj+1], a2 = faces[3*fj+2];
            float ax = verts[3*a0+0], ay = verts[3*a0+1], az = verts[3*a0+2];
            float bx = verts[3*a1+0], by = verts[3*a1+1], bz = verts[3*a1+2];
            float cx = verts[3*a2+0], cy = verts[3*a2+1], cz = verts[3*a2+2];

            float e1x = bx-ax, e1y = by-ay, e1z = bz-az;   // b-a
            float e2x = cx-ax, e2y = cy-ay, e2z = cz-az;   // c-a
            float nx = e1y*e2z - e1z*e2y;
            float ny = e1z*e2x - e1x*e2z;
            float nz = e1x*e2y - e1y*e2x;
            float area = 0.5f * sqrtf(nx*nx + ny*ny + nz*nz);

            // uc = dot(cross(c-b, p-b), n)
            float cbx = cx-bx, cby = cy-by, cbz = cz-bz;
            float pbx = px-bx, pby = py-by, pbz = pz-bz;
            float uc = (cby*pbz - cbz*pby)*nx + (cbz*pbx - cbx*pbz)*ny + (cbx*pby - cby*pbx)*nz;

            // vc = dot(cross(a-c, p-c), n)
            float acx = ax-cx, acy = ay-cy, acz = az-cz;
            float pcx = px-cx, pcy = py-cy, pcz = pz-cz;
            float vc = (acy*pcz - acz*pcy)*nx + (acz*pcx - acx*pcz)*ny + (acx*pcy - acy*pcx)*nz;

            // wc = dot(cross(b-a, p-a), n)
            float pax = px-ax, pay = py-ay, paz = pz-az;
            float wc = (e1y*paz - e1z*pay)*nx + (e1z*pax - e1x*paz)*ny + (e1x*pay - e1y*pax)*nz;

            if (fabsf(area) > FEPS && uc >= 0.0f && vc >= 0.0f && wc >= 0.0f)
                psum += area;
        }
    }

    // wave reduce (64-wide), then block reduce, one atomic per block
    #pragma unroll
    for (int off = 32; off > 0; off >>= 1)
        psum += __shfl_down(psum, off, 64);
    int wid = threadIdx.x >> 6;
    if ((threadIdx.x & 63) == 0) wsum[wid] = psum;
    __syncthreads();
    if (threadIdx.x == 0)
        atomicAdd(out, wsum[0] + wsum[1] + wsum[2] + wsum[3]);
}

extern "C" void kernel_launch(void* const* d_in, const int* in_sizes, int n_in,
                              void* d_out, int out_size, void* d_ws, size_t ws_size,
                              hipStream_t stream) {
    const float* verts = (const float*)d_in[0];
    const int*   faces = (const int*)d_in[1];
    const float* u     = (const float*)d_in[2];
    const float* v     = (const float*)d_in[3];
    float*       out   = (float*)d_out;

    int F = in_sizes[1] / 3;    // 6000
    int N = in_sizes[2];        // F * S = 60000

    // graph replays accumulate via atomicAdd -> zero the output every launch
    hipMemsetAsync(d_out, 0, sizeof(float), stream);

    int blocks = (N + 255) / 256;
    otl_kernel<<<blocks, 256, 0, stream>>>(verts, faces, u, v, out, F, N);
}

// Round 4
// 188.492 us; speedup vs baseline: 2.9452x; 2.9452x over previous
//
#include <hip/hip_runtime.h>
#include <float.h>

#define KNN   5
#define FEPS  1e-6f
#define NSAMP 10
#define NWAVE 8     // waves per block == centroid chunks
#define PPB   64    // points per block (lane == point)

__global__ __launch_bounds__(256) void centroid_kernel(
    const float* __restrict__ verts, const int* __restrict__ faces,
    float4* __restrict__ cent, int F)
{
    int i = blockIdx.x * blockDim.x + threadIdx.x;
    if (i < F) {
        int i0 = faces[3*i], i1 = faces[3*i+1], i2 = faces[3*i+2];
        float cx = (verts[3*i0+0] + verts[3*i1+0] + verts[3*i2+0]) * (1.0f/3.0f);
        float cy = (verts[3*i0+1] + verts[3*i1+1] + verts[3*i2+1]) * (1.0f/3.0f);
        float cz = (verts[3*i0+2] + verts[3*i1+2] + verts[3*i2+2]) * (1.0f/3.0f);
        float h  = fmaf(cx, cx, fmaf(cy, cy, cz*cz));   // |C|^2
        cent[i] = make_float4(cx, cy, cz, h);
    }
}

__global__ __launch_bounds__(512, 4) void scan_kernel(
    const float* __restrict__ verts, const int* __restrict__ faces,
    const float* __restrict__ uarr, const float* __restrict__ varr,
    const float4* __restrict__ cent,
    float* __restrict__ out, int F, int N)
{
    __shared__ uint2 cand[KNN][NWAVE][64];   // [slot][wave][lane] -> 8B lane stride, conflict-free
    __shared__ float wsum[NWAVE];

    const int  lane  = threadIdx.x & 63;
    const int  w     = threadIdx.x >> 6;
    const int  p     = blockIdx.x * PPB + lane;
    const bool valid = p < N;
    const int  pc    = valid ? p : N - 1;       // clamp for safe loads

    // ---- compute this lane's sample point P (redundant across waves, cheap) ----
    float uu = uarr[pc], vv = varr[pc];
    if (uu + vv > 1.0f) { uu = 1.0f - uu; vv = 1.0f - vv; }
    float w0 = 1.0f - uu - vv;
    int  f  = pc / NSAMP;
    int  i0 = faces[3*f], i1 = faces[3*f+1], i2 = faces[3*f+2];
    float px = verts[3*i0+0]*w0 + verts[3*i1+0]*uu + verts[3*i2+0]*vv;
    float py = verts[3*i0+1]*w0 + verts[3*i1+1]*uu + verts[3*i2+1]*vv;
    float pz = verts[3*i0+2]*w0 + verts[3*i1+2]*uu + verts[3*i2+2]*vv;
    float qx = -2.0f*px, qy = -2.0f*py, qz = -2.0f*pz;

    // ---- wave-uniform centroid chunk; force SGPR so loads become s_load ----
    int c0 = __builtin_amdgcn_readfirstlane((F *  w     ) / NWAVE);
    int c1 = __builtin_amdgcn_readfirstlane((F * (w + 1)) / NWAVE);

    // score = |C|^2 - 2 P.C  (= d2 - |P|^2; same argmin ordering per point)
    float d0=FLT_MAX,d1=FLT_MAX,d2=FLT_MAX,d3=FLT_MAX,d4=FLT_MAX;
    int   j0=0x7FFFFFFF,j1=0x7FFFFFFF,j2=0x7FFFFFFF,j3=0x7FFFFFFF,j4=0x7FFFFFFF;

    #pragma unroll 4
    for (int j = c0; j < c1; ++j) {
        float4 c = cent[j];   // wave-uniform -> s_load_dwordx4 (SGPR broadcast)
        float s = fmaf(qx, c.x, fmaf(qy, c.y, fmaf(qz, c.z, c.w)));
        if (s < d4) {                      // rare insert, exec-masked
            if (s < d3) {
                d4 = d3; j4 = j3;
                if (s < d2) {
                    d3 = d2; j3 = j2;
                    if (s < d1) {
                        d2 = d1; j2 = j1;
                        if (s < d0) { d1 = d0; j1 = j0; d0 = s; j0 = j; }
                        else        { d1 = s;  j1 = j; }
                    } else { d2 = s; j2 = j; }
                } else { d3 = s; j3 = j; }
            } else { d4 = s; j4 = j; }
        }
    }

    cand[0][w][lane] = make_uint2(__float_as_uint(d0), (unsigned)j0);
    cand[1][w][lane] = make_uint2(__float_as_uint(d1), (unsigned)j1);
    cand[2][w][lane] = make_uint2(__float_as_uint(d2), (unsigned)j2);
    cand[3][w][lane] = make_uint2(__float_as_uint(d3), (unsigned)j3);
    cand[4][w][lane] = make_uint2(__float_as_uint(d4), (unsigned)j4);
    __syncthreads();

    // ---- merge the 8 partial top-5 lists (redundant per wave, ~240 ops) ----
    float m0=FLT_MAX,m1=FLT_MAX,m2=FLT_MAX,m3=FLT_MAX,m4=FLT_MAX;
    int   n0=0x7FFFFFFF,n1=0x7FFFFFFF,n2=0x7FFFFFFF,n3=0x7FFFFFFF,n4=0x7FFFFFFF;
    #define LEX(s,ix,dk,jk) ((s) < (dk) || ((s) == (dk) && (ix) < (jk)))
    for (int cw = 0; cw < NWAVE; ++cw) {
        #pragma unroll
        for (int k = 0; k < KNN; ++k) {
            uint2 e = cand[k][cw][lane];
            float s = __uint_as_float(e.x);
            int  ix = (int)e.y;
            if (LEX(s, ix, m4, n4)) {
                if (LEX(s, ix, m3, n3)) {
                    m4 = m3; n4 = n3;
                    if (LEX(s, ix, m2, n2)) {
                        m3 = m2; n3 = n2;
                        if (LEX(s, ix, m1, n1)) {
                            m2 = m1; n2 = n1;
                            if (LEX(s, ix, m0, n0)) { m1 = m0; n1 = n0; m0 = s; n0 = ix; }
                            else                    { m1 = s;  n1 = ix; }
                        } else { m2 = s; n2 = ix; }
                    } else { m3 = s; n3 = ix; }
                } else { m4 = s; n4 = ix; }
            }
        }
    }
    #undef LEX

    // ---- epilogue: wave w (<5) tests its slot's triangle for its lane's point ----
    float psum = 0.0f;
    if (valid && w < KNN) {
        int fj = (w == 0) ? n0 : (w == 1) ? n1 : (w == 2) ? n2 : (w == 3) ? n3 : n4;
        int a0 = faces[3*fj], a1 = faces[3*fj+1], a2 = faces[3*fj+2];
        float ax = verts[3*a0+0], ay = verts[3*a0+1], az = verts[3*a0+2];
        float bx = verts[3*a1+0], by = verts[3*a1+1], bz = verts[3*a1+2];
        float cx = verts[3*a2+0], cy = verts[3*a2+1], cz = verts[3*a2+2];

        float e1x = bx-ax, e1y = by-ay, e1z = bz-az;   // b-a
        float e2x = cx-ax, e2y = cy-ay, e2z = cz-az;   // c-a
        float nx = e1y*e2z - e1z*e2y;
        float ny = e1z*e2x - e1x*e2z;
        float nz = e1x*e2y - e1y*e2x;
        float area = 0.5f * sqrtf(nx*nx + ny*ny + nz*nz);

        float cbx = cx-bx, cby = cy-by, cbz = cz-bz;
        float pbx = px-bx, pby = py-by, pbz = pz-bz;
        float uc = (cby*pbz - cbz*pby)*nx + (cbz*pbx - cbx*pbz)*ny + (cbx*pby - cby*pbx)*nz;

        float acx = ax-cx, acy = ay-cy, acz = az-cz;
        float pcx = px-cx, pcy = py-cy, pcz = pz-cz;
        float vc = (acy*pcz - acz*pcy)*nx + (acz*pcx - acx*pcz)*ny + (acx*pcy - acy*pcx)*nz;

        float pax = px-ax, pay = py-ay, paz = pz-az;
        float wc = (e1y*paz - e1z*pay)*nx + (e1z*pax - e1x*paz)*ny + (e1x*pay - e1y*pax)*nz;

        if (fabsf(area) > FEPS && uc >= 0.0f && vc >= 0.0f && wc >= 0.0f)
            psum = area;
    }

    // ---- reduce: 64-wide shuffle, then across the 8 waves, one atomic/block ----
    #pragma unroll
    for (int off = 32; off > 0; off >>= 1)
        psum += __shfl_down(psum, off, 64);
    if (lane == 0) wsum[w] = psum;
    __syncthreads();
    if (threadIdx.x == 0) {
        float t = 0.0f;
        #pragma unroll
        for (int i = 0; i < NWAVE; ++i) t += wsum[i];
        atomicAdd(out, t);
    }
}

extern "C" void kernel_launch(void* const* d_in, const int* in_sizes, int n_in,
                              void* d_out, int out_size, void* d_ws, size_t ws_size,
                              hipStream_t stream) {
    const float* verts = (const float*)d_in[0];
    const int*   faces = (const int*)d_in[1];
    const float* u     = (const float*)d_in[2];
    const float* v     = (const float*)d_in[3];
    float*       out   = (float*)d_out;
    float4*      cent  = (float4*)d_ws;    // F * 16 bytes = 96 KB scratch

    int F = in_sizes[1] / 3;    // 6000
    int N = in_sizes[2];        // 60000

    hipMemsetAsync(d_out, 0, sizeof(float), stream);   // atomic accumulator
    centroid_kernel<<<(F + 255) / 256, 256, 0, stream>>>(verts, faces, cent, F);
    int blocks = (N + PPB - 1) / PPB;                  // 938
    scan_kernel<<<blocks, 512, 0, stream>>>(verts, faces, u, v, cent, out, F, N);
}

// Round 5
// 167.939 us; speedup vs baseline: 3.3057x; 1.1224x over previous
//
#include <hip/hip_runtime.h>
#include <float.h>

#define KNN   5
#define FEPS  1e-6f
#define NSAMP 10
#define NWAVE 8     // waves per block == centroid chunks
#define PPB   64    // points per block (lane == point)

static __device__ __forceinline__ unsigned umn(unsigned a, unsigned b){ return a < b ? a : b; }
static __device__ __forceinline__ unsigned umx(unsigned a, unsigned b){ return a > b ? a : b; }

__global__ __launch_bounds__(256) void centroid_kernel(
    const float* __restrict__ verts, const int* __restrict__ faces,
    float4* __restrict__ cent, int F)
{
    int i = blockIdx.x * blockDim.x + threadIdx.x;
    if (i < F) {
        int i0 = faces[3*i], i1 = faces[3*i+1], i2 = faces[3*i+2];
        float cx = (verts[3*i0+0] + verts[3*i1+0] + verts[3*i2+0]) * (1.0f/3.0f);
        float cy = (verts[3*i0+1] + verts[3*i1+1] + verts[3*i2+1]) * (1.0f/3.0f);
        float cz = (verts[3*i0+2] + verts[3*i1+2] + verts[3*i2+2]) * (1.0f/3.0f);
        float h  = fmaf(cx, cx, fmaf(cy, cy, cz*cz));   // |C|^2
        cent[i] = make_float4(cx, cy, cz, h);
    }
}

__global__ __launch_bounds__(512, 4) void scan_kernel(
    const float* __restrict__ verts, const int* __restrict__ faces,
    const float* __restrict__ uarr, const float* __restrict__ varr,
    const float4* __restrict__ cent,
    float* __restrict__ out, int F, int N)
{
    __shared__ unsigned cand[KNN][NWAVE][64];   // u32 packed (score|idx); 4B lane stride = 2-way = free
    __shared__ float wsum[NWAVE];

    const int  lane  = threadIdx.x & 63;
    const int  w     = threadIdx.x >> 6;
    const int  p     = blockIdx.x * PPB + lane;
    const bool valid = p < N;
    const int  pc    = valid ? p : N - 1;       // clamp for safe loads

    // ---- this lane's sample point P (redundant across waves, cheap) ----
    float uu = uarr[pc], vv = varr[pc];
    if (uu + vv > 1.0f) { uu = 1.0f - uu; vv = 1.0f - vv; }
    float w0 = 1.0f - uu - vv;
    int  f  = pc / NSAMP;
    int  i0 = faces[3*f], i1 = faces[3*f+1], i2 = faces[3*f+2];
    float px = verts[3*i0+0]*w0 + verts[3*i1+0]*uu + verts[3*i2+0]*vv;
    float py = verts[3*i0+1]*w0 + verts[3*i1+1]*uu + verts[3*i2+1]*vv;
    float pz = verts[3*i0+2]*w0 + verts[3*i1+2]*uu + verts[3*i2+2]*vv;
    float qx = -2.0f*px, qy = -2.0f*py, qz = -2.0f*pz;
    float pp = fmaf(px, px, fmaf(py, py, pz*pz));      // |P|^2

    // ---- wave-uniform centroid chunk -> s_load broadcasts ----
    int c0 = __builtin_amdgcn_readfirstlane((F *  w     ) / NWAVE);
    int c1 = __builtin_amdgcn_readfirstlane((F * (w + 1)) / NWAVE);

    // packed key: [31:13] = high bits of float(d^2) (d^2>=0 so bit order == value order),
    //             [12:0]  = centroid index  -> u32 compare == lexicographic (d2, idx)
    unsigned k0=0xFFFFFFFFu,k1=0xFFFFFFFFu,k2=0xFFFFFFFFu,k3=0xFFFFFFFFu,k4=0xFFFFFFFFu;

    #pragma unroll 4
    for (int j = c0; j < c1; ++j) {
        float4 c = cent[j];   // wave-uniform -> s_load_dwordx4
        float s = fmaf(qx, c.x, fmaf(qy, c.y, fmaf(qz, c.z, c.w))) + pp;  // d^2 (+rounding)
        s = fmaxf(s, 0.0f);                                               // keep sign bit 0
        unsigned u = (__float_as_uint(s) & 0xFFFFE000u) | (unsigned)j;
        // branchless sorted insert, 9 ops
        unsigned t;
        t = umn(k0,u); u = umx(k0,u); k0 = t;
        t = umn(k1,u); u = umx(k1,u); k1 = t;
        t = umn(k2,u); u = umx(k2,u); k2 = t;
        t = umn(k3,u); u = umx(k3,u); k3 = t;
        k4 = umn(k4,u);
    }

    cand[0][w][lane] = k0;
    cand[1][w][lane] = k1;
    cand[2][w][lane] = k2;
    cand[3][w][lane] = k3;
    cand[4][w][lane] = k4;
    __syncthreads();

    // ---- merge the 8 partial sorted top-5 lists (only waves 0..4 need it) ----
    float psum = 0.0f;
    if (valid && w < KNN) {
        unsigned m0=0xFFFFFFFFu,m1=0xFFFFFFFFu,m2=0xFFFFFFFFu,m3=0xFFFFFFFFu,m4=0xFFFFFFFFu;
        for (int cw = 0; cw < NWAVE; ++cw) {
            #pragma unroll
            for (int k = 0; k < KNN; ++k) {
                unsigned u = cand[k][cw][lane], t;
                t = umn(m0,u); u = umx(m0,u); m0 = t;
                t = umn(m1,u); u = umx(m1,u); m1 = t;
                t = umn(m2,u); u = umx(m2,u); m2 = t;
                t = umn(m3,u); u = umx(m3,u); m3 = t;
                m4 = umn(m4,u);
            }
        }
        // wave w tests slot w's triangle for its lane's point
        unsigned mw = (w == 0) ? m0 : (w == 1) ? m1 : (w == 2) ? m2 : (w == 3) ? m3 : m4;
        int fj = (int)(mw & 0x1FFFu);

        int a0 = faces[3*fj], a1 = faces[3*fj+1], a2 = faces[3*fj+2];
        float ax = verts[3*a0+0], ay = verts[3*a0+1], az = verts[3*a0+2];
        float bx = verts[3*a1+0], by = verts[3*a1+1], bz = verts[3*a1+2];
        float cx = verts[3*a2+0], cy = verts[3*a2+1], cz = verts[3*a2+2];

        float e1x = bx-ax, e1y = by-ay, e1z = bz-az;   // b-a
        float e2x = cx-ax, e2y = cy-ay, e2z = cz-az;   // c-a
        float nx = e1y*e2z - e1z*e2y;
        float ny = e1z*e2x - e1x*e2z;
        float nz = e1x*e2y - e1y*e2x;
        float area = 0.5f * sqrtf(nx*nx + ny*ny + nz*nz);

        float cbx = cx-bx, cby = cy-by, cbz = cz-bz;
        float pbx = px-bx, pby = py-by, pbz = pz-bz;
        float uc = (cby*pbz - cbz*pby)*nx + (cbz*pbx - cbx*pbz)*ny + (cbx*pby - cby*pbx)*nz;

        float acx = ax-cx, acy = ay-cy, acz = az-cz;
        float pcx = px-cx, pcy = py-cy, pcz = pz-cz;
        float vc = (acy*pcz - acz*pcy)*nx + (acz*pcx - acx*pcz)*ny + (acx*pcy - acy*pcx)*nz;

        float pax = px-ax, pay = py-ay, paz = pz-az;
        float wc = (e1y*paz - e1z*pay)*nx + (e1z*pax - e1x*paz)*ny + (e1x*pay - e1y*pax)*nz;

        if (fabsf(area) > FEPS && uc >= 0.0f && vc >= 0.0f && wc >= 0.0f)
            psum = area;
    }

    // ---- reduce: 64-wide shuffle, across 8 waves, one atomic/block ----
    #pragma unroll
    for (int off = 32; off > 0; off >>= 1)
        psum += __shfl_down(psum, off, 64);
    if (lane == 0) wsum[w] = psum;
    __syncthreads();
    if (threadIdx.x == 0) {
        float t = 0.0f;
        #pragma unroll
        for (int i = 0; i < NWAVE; ++i) t += wsum[i];
        atomicAdd(out, t);
    }
}

extern "C" void kernel_launch(void* const* d_in, const int* in_sizes, int n_in,
                              void* d_out, int out_size, void* d_ws, size_t ws_size,
                              hipStream_t stream) {
    const float* verts = (const float*)d_in[0];
    const int*   faces = (const int*)d_in[1];
    const float* u     = (const float*)d_in[2];
    const float* v     = (const float*)d_in[3];
    float*       out   = (float*)d_out;
    float4*      cent  = (float4*)d_ws;    // F * 16 bytes = 96 KB scratch

    int F = in_sizes[1] / 3;    // 6000
    int N = in_sizes[2];        // 60000

    hipMemsetAsync(d_out, 0, sizeof(float), stream);   // atomic accumulator
    centroid_kernel<<<(F + 255) / 256, 256, 0, stream>>>(verts, faces, cent, F);
    int blocks = (N + PPB - 1) / PPB;                  // 938
    scan_kernel<<<blocks, 512, 0, stream>>>(verts, faces, u, v, cent, out, F, N);
}

// Round 6
// 159.563 us; speedup vs baseline: 3.4792x; 1.0525x over previous
//
#include <hip/hip_runtime.h>
#include <float.h>

#define KNN   5
#define FEPS  1e-6f
#define NSAMP 10
#define NWAVE 8     // waves per block == centroid chunks
#define PPB   64    // points per block (lane == point)

static __device__ __forceinline__ unsigned umn(unsigned a, unsigned b){ return __builtin_elementwise_min(a, b); }
static __device__ __forceinline__ unsigned umx(unsigned a, unsigned b){ return __builtin_elementwise_max(a, b); }

__global__ __launch_bounds__(256) void centroid_kernel(
    const float* __restrict__ verts, const int* __restrict__ faces,
    float4* __restrict__ cent, int F, int Fpad)
{
    int i = blockIdx.x * blockDim.x + threadIdx.x;
    if (i < F) {
        int i0 = faces[3*i], i1 = faces[3*i+1], i2 = faces[3*i+2];
        float cx = (verts[3*i0+0] + verts[3*i1+0] + verts[3*i2+0]) * (1.0f/3.0f);
        float cy = (verts[3*i0+1] + verts[3*i1+1] + verts[3*i2+1]) * (1.0f/3.0f);
        float cz = (verts[3*i0+2] + verts[3*i1+2] + verts[3*i2+2]) * (1.0f/3.0f);
        float h  = fmaf(cx, cx, fmaf(cy, cy, cz*cz));   // |C|^2
        cent[i] = make_float4(cx, cy, cz, h);
    } else if (i < Fpad) {
        cent[i] = make_float4(0.0f, 0.0f, 0.0f, 3.0e38f);  // sentinel: never selected
    }
}

__global__ __launch_bounds__(512, 8) void scan_kernel(
    const float* __restrict__ verts, const int* __restrict__ faces,
    const float* __restrict__ uarr, const float* __restrict__ varr,
    const float4* __restrict__ cent,
    float* __restrict__ out, int CH, int N)
{
    __shared__ unsigned cand[KNN][NWAVE][64];   // 4B lane stride = 2-way = free
    __shared__ float wsum[NWAVE];

    const int  lane  = threadIdx.x & 63;
    const int  w     = threadIdx.x >> 6;
    const int  p     = blockIdx.x * PPB + lane;
    const bool valid = p < N;
    const int  pc    = valid ? p : N - 1;       // clamp for safe loads

    // ---- this lane's sample point P (redundant across waves, cheap) ----
    float uu = uarr[pc], vv = varr[pc];
    if (uu + vv > 1.0f) { uu = 1.0f - uu; vv = 1.0f - vv; }
    float w0 = 1.0f - uu - vv;
    int  f  = pc / NSAMP;
    int  i0 = faces[3*f], i1 = faces[3*f+1], i2 = faces[3*f+2];
    float px = verts[3*i0+0]*w0 + verts[3*i1+0]*uu + verts[3*i2+0]*vv;
    float py = verts[3*i0+1]*w0 + verts[3*i1+1]*uu + verts[3*i2+1]*vv;
    float pz = verts[3*i0+2]*w0 + verts[3*i1+2]*uu + verts[3*i2+2]*vv;
    float qx = -2.0f*px, qy = -2.0f*py, qz = -2.0f*pz;
    float pp = fmaf(px, px, fmaf(py, py, pz*pz));      // |P|^2

    // ---- wave-uniform centroid chunk of size CH (multiple of 4) ----
    const int c0 = __builtin_amdgcn_readfirstlane(CH * w);
    const float4* __restrict__ cw = cent + c0;

    // packed key: [31:13] = high bits of float(d^2) (>=0 so bit order == value),
    //             [12:0]  = centroid index -> u32 compare == lex (d2, idx)
    unsigned k0=0xFFFFFFFFu,k1=0xFFFFFFFFu,k2=0xFFFFFFFFu,k3=0xFFFFFFFFu,k4=0xFFFFFFFFu;

    #pragma unroll 4
    for (int t = 0; t < CH; ++t) {
        float4 c = cw[t];
        float s = fmaf(qx, c.x, fmaf(qy, c.y, fmaf(qz, c.z, c.w))) + pp;  // d^2
        s = fmaxf(s, 0.0f);                                               // sign bit 0
        unsigned u = (__float_as_uint(s) & 0xFFFFE000u) | (unsigned)(c0 + t);
        unsigned tt;
        tt = umn(k0,u); u = umx(k0,u); k0 = tt;
        tt = umn(k1,u); u = umx(k1,u); k1 = tt;
        tt = umn(k2,u); u = umx(k2,u); k2 = tt;
        tt = umn(k3,u); u = umx(k3,u); k3 = tt;
        k4 = umn(k4,u);
    }

    cand[0][w][lane] = k0;
    cand[1][w][lane] = k1;
    cand[2][w][lane] = k2;
    cand[3][w][lane] = k3;
    cand[4][w][lane] = k4;
    __syncthreads();

    // ---- merge the 8 partial sorted top-5 lists (only waves 0..4) ----
    float psum = 0.0f;
    if (valid && w < KNN) {
        unsigned m0=0xFFFFFFFFu,m1=0xFFFFFFFFu,m2=0xFFFFFFFFu,m3=0xFFFFFFFFu,m4=0xFFFFFFFFu;
        for (int cw2 = 0; cw2 < NWAVE; ++cw2) {
            #pragma unroll
            for (int k = 0; k < KNN; ++k) {
                unsigned u = cand[k][cw2][lane], tt;
                tt = umn(m0,u); u = umx(m0,u); m0 = tt;
                tt = umn(m1,u); u = umx(m1,u); m1 = tt;
                tt = umn(m2,u); u = umx(m2,u); m2 = tt;
                tt = umn(m3,u); u = umx(m3,u); m3 = tt;
                m4 = umn(m4,u);
            }
        }
        // wave w tests slot w's triangle for its lane's point
        unsigned mw = (w == 0) ? m0 : (w == 1) ? m1 : (w == 2) ? m2 : (w == 3) ? m3 : m4;
        int fj = (int)(mw & 0x1FFFu);

        int a0 = faces[3*fj], a1 = faces[3*fj+1], a2 = faces[3*fj+2];
        float ax = verts[3*a0+0], ay = verts[3*a0+1], az = verts[3*a0+2];
        float bx = verts[3*a1+0], by = verts[3*a1+1], bz = verts[3*a1+2];
        float cx = verts[3*a2+0], cy = verts[3*a2+1], cz = verts[3*a2+2];

        float e1x = bx-ax, e1y = by-ay, e1z = bz-az;   // b-a
        float e2x = cx-ax, e2y = cy-ay, e2z = cz-az;   // c-a
        float nx = e1y*e2z - e1z*e2y;
        float ny = e1z*e2x - e1x*e2z;
        float nz = e1x*e2y - e1y*e2x;
        float area = 0.5f * sqrtf(nx*nx + ny*ny + nz*nz);

        float cbx = cx-bx, cby = cy-by, cbz = cz-bz;
        float pbx = px-bx, pby = py-by, pbz = pz-bz;
        float uc = (cby*pbz - cbz*pby)*nx + (cbz*pbx - cbx*pbz)*ny + (cbx*pby - cby*pbx)*nz;

        float acx = ax-cx, acy = ay-cy, acz = az-cz;
        float pcx = px-cx, pcy = py-cy, pcz = pz-cz;
        float vc = (acy*pcz - acz*pcy)*nx + (acz*pcx - acx*pcz)*ny + (acx*pcy - acy*pcx)*nz;

        float pax = px-ax, pay = py-ay, paz = pz-az;
        float wc = (e1y*paz - e1z*pay)*nx + (e1z*pax - e1x*paz)*ny + (e1x*pay - e1y*pax)*nz;

        if (fabsf(area) > FEPS && uc >= 0.0f && vc >= 0.0f && wc >= 0.0f)
            psum = area;
    }

    // ---- reduce: 64-wide shuffle, across 8 waves, one atomic/block ----
    #pragma unroll
    for (int off = 32; off > 0; off >>= 1)
        psum += __shfl_down(psum, off, 64);
    if (lane == 0) wsum[w] = psum;
    __syncthreads();
    if (threadIdx.x == 0) {
        float t = 0.0f;
        #pragma unroll
        for (int i = 0; i < NWAVE; ++i) t += wsum[i];
        atomicAdd(out, t);
    }
}

extern "C" void kernel_launch(void* const* d_in, const int* in_sizes, int n_in,
                              void* d_out, int out_size, void* d_ws, size_t ws_size,
                              hipStream_t stream) {
    const float* verts = (const float*)d_in[0];
    const int*   faces = (const int*)d_in[1];
    const float* u     = (const float*)d_in[2];
    const float* v     = (const float*)d_in[3];
    float*       out   = (float*)d_out;
    float4*      cent  = (float4*)d_ws;

    int F = in_sizes[1] / 3;    // 6000
    int N = in_sizes[2];        // 60000
    int Fpad = ((F + NWAVE*4 - 1) / (NWAVE*4)) * (NWAVE*4);   // 6016 -> chunk 752 = 4*188
    int CH   = Fpad / NWAVE;

    hipMemsetAsync(d_out, 0, sizeof(float), stream);   // atomic accumulator
    centroid_kernel<<<(Fpad + 255) / 256, 256, 0, stream>>>(verts, faces, cent, F, Fpad);
    int blocks = (N + PPB - 1) / PPB;                  // 938
    scan_kernel<<<blocks, 512, 0, stream>>>(verts, faces, u, v, cent, out, CH, N);
}

// Round 7
// 131.301 us; speedup vs baseline: 4.2281x; 1.2153x over previous
//
#include <hip/hip_runtime.h>
#include <float.h>

#define KNN   5
#define FEPS  1e-6f
#define NSAMP 10
#define NWAVE 8     // waves per block == centroid chunks
#define PPB   64    // points per block (lane == point)

static __device__ __forceinline__ unsigned umn(unsigned a, unsigned b){ return __builtin_elementwise_min(a, b); }
static __device__ __forceinline__ unsigned umx(unsigned a, unsigned b){ return __builtin_elementwise_max(a, b); }
// v_med3_u32: median of 3 — single VOP3, no builtin exposed, use asm.
static __device__ __forceinline__ unsigned med3u(unsigned a, unsigned b, unsigned c){
    unsigned r; asm("v_med3_u32 %0, %1, %2, %3" : "=v"(r) : "v"(a), "v"(b), "v"(c)); return r;
}

__global__ __launch_bounds__(256) void centroid_kernel(
    const float* __restrict__ verts, const int* __restrict__ faces,
    float4* __restrict__ cent, int F, int Fpad)
{
    int i = blockIdx.x * blockDim.x + threadIdx.x;
    if (i < F) {
        int i0 = faces[3*i], i1 = faces[3*i+1], i2 = faces[3*i+2];
        float cx = (verts[3*i0+0] + verts[3*i1+0] + verts[3*i2+0]) * (1.0f/3.0f);
        float cy = (verts[3*i0+1] + verts[3*i1+1] + verts[3*i2+1]) * (1.0f/3.0f);
        float cz = (verts[3*i0+2] + verts[3*i1+2] + verts[3*i2+2]) * (1.0f/3.0f);
        float h  = fmaf(cx, cx, fmaf(cy, cy, cz*cz));   // |C|^2
        cent[i] = make_float4(cx, cy, cz, h);
    } else if (i < Fpad) {
        cent[i] = make_float4(0.0f, 0.0f, 0.0f, 3.0e38f);  // sentinel: never selected
    }
}

__global__ __launch_bounds__(512, 6) void scan_kernel(
    const float* __restrict__ verts, const int* __restrict__ faces,
    const float* __restrict__ uarr, const float* __restrict__ varr,
    const float4* __restrict__ cent,
    float* __restrict__ out, int CH, int N)
{
    __shared__ unsigned cand[KNN][NWAVE][64];   // 4B lane stride = 2-way = free
    __shared__ float wsum[NWAVE];

    const int  lane  = threadIdx.x & 63;
    const int  w     = threadIdx.x >> 6;
    const int  p     = blockIdx.x * PPB + lane;
    const bool valid = p < N;
    const int  pc    = valid ? p : N - 1;       // clamp for safe loads

    // ---- this lane's sample point P (redundant across waves, cheap) ----
    float uu = uarr[pc], vv = varr[pc];
    if (uu + vv > 1.0f) { uu = 1.0f - uu; vv = 1.0f - vv; }
    float w0 = 1.0f - uu - vv;
    int  f  = pc / NSAMP;
    int  i0 = faces[3*f], i1 = faces[3*f+1], i2 = faces[3*f+2];
    float px = verts[3*i0+0]*w0 + verts[3*i1+0]*uu + verts[3*i2+0]*vv;
    float py = verts[3*i0+1]*w0 + verts[3*i1+1]*uu + verts[3*i2+1]*vv;
    float pz = verts[3*i0+2]*w0 + verts[3*i1+2]*uu + verts[3*i2+2]*vv;
    float qx = -2.0f*px, qy = -2.0f*py, qz = -2.0f*pz;
    float pp = fmaf(px, px, fmaf(py, py, pz*pz));      // |P|^2

    // ---- wave-uniform centroid chunk of size CH (multiple of 8) ----
    const int c0 = __builtin_amdgcn_readfirstlane(CH * w);
    const float4* __restrict__ cw = cent + c0;

    // packed key: [31:13] = high float bits of d^2 (>=0, so bit order == value),
    //             [12:0]  = global centroid index -> u32 compare == lex (d2, idx)
    unsigned k0=0xFFFFFFFFu,k1=0xFFFFFFFFu,k2=0xFFFFFFFFu,k3=0xFFFFFFFFu,k4=0xFFFFFFFFu;

    #pragma unroll 8
    for (int t = 0; t < CH; ++t) {
        float4 c = cw[t];                 // wave-uniform -> s_load_dwordx4
        float h = c.w + pp;               // |C|^2 + |P|^2  (v_add: 1 SGPR ok)
        float s = fmaf(qx, c.x, fmaf(qy, c.y, fmaf(qz, c.z, h)));  // d^2
        s = fmaxf(s, 0.0f);               // clamp cancellation; keep sign bit 0
        unsigned u = (__float_as_uint(s) & 0xFFFFE000u) | (unsigned)(c0 + t);
        // 5-op sorted insert via med3 (all independent)
        unsigned n4 = med3u(k3, k4, u);
        unsigned n3 = med3u(k2, k3, u);
        unsigned n2 = med3u(k1, k2, u);
        unsigned n1 = med3u(k0, k1, u);
        k0 = umn(k0, u); k1 = n1; k2 = n2; k3 = n3; k4 = n4;
    }

    cand[0][w][lane] = k0;
    cand[1][w][lane] = k1;
    cand[2][w][lane] = k2;
    cand[3][w][lane] = k3;
    cand[4][w][lane] = k4;
    __syncthreads();

    // ---- merge the 8 partial sorted top-5 lists (only waves 0..4) ----
    float psum = 0.0f;
    if (valid && w < KNN) {
        unsigned m0=0xFFFFFFFFu,m1=0xFFFFFFFFu,m2=0xFFFFFFFFu,m3=0xFFFFFFFFu,m4=0xFFFFFFFFu;
        for (int cw2 = 0; cw2 < NWAVE; ++cw2) {
            #pragma unroll
            for (int k = 0; k < KNN; ++k) {
                unsigned u = cand[k][cw2][lane];
                unsigned n4 = med3u(m3, m4, u);
                unsigned n3 = med3u(m2, m3, u);
                unsigned n2 = med3u(m1, m2, u);
                unsigned n1 = med3u(m0, m1, u);
                m0 = umn(m0, u); m1 = n1; m2 = n2; m3 = n3; m4 = n4;
            }
        }
        // wave w tests slot w's triangle for its lane's point
        unsigned mw = (w == 0) ? m0 : (w == 1) ? m1 : (w == 2) ? m2 : (w == 3) ? m3 : m4;
        int fj = (int)(mw & 0x1FFFu);

        int a0 = faces[3*fj], a1 = faces[3*fj+1], a2 = faces[3*fj+2];
        float ax = verts[3*a0+0], ay = verts[3*a0+1], az = verts[3*a0+2];
        float bx = verts[3*a1+0], by = verts[3*a1+1], bz = verts[3*a1+2];
        float cx = verts[3*a2+0], cy = verts[3*a2+1], cz = verts[3*a2+2];

        float e1x = bx-ax, e1y = by-ay, e1z = bz-az;   // b-a
        float e2x = cx-ax, e2y = cy-ay, e2z = cz-az;   // c-a
        float nx = e1y*e2z - e1z*e2y;
        float ny = e1z*e2x - e1x*e2z;
        float nz = e1x*e2y - e1y*e2x;
        float area = 0.5f * sqrtf(nx*nx + ny*ny + nz*nz);

        float cbx = cx-bx, cby = cy-by, cbz = cz-bz;
        float pbx = px-bx, pby = py-by, pbz = pz-bz;
        float uc = (cby*pbz - cbz*pby)*nx + (cbz*pbx - cbx*pbz)*ny + (cbx*pby - cby*pbx)*nz;

        float acx = ax-cx, acy = ay-cy, acz = az-cz;
        float pcx = px-cx, pcy = py-cy, pcz = pz-cz;
        float vc = (acy*pcz - acz*pcy)*nx + (acz*pcx - acx*pcz)*ny + (acx*pcy - acy*pcx)*nz;

        float pax = px-ax, pay = py-ay, paz = pz-az;
        float wc = (e1y*paz - e1z*pay)*nx + (e1z*pax - e1x*paz)*ny + (e1x*pay - e1y*pax)*nz;

        if (fabsf(area) > FEPS && uc >= 0.0f && vc >= 0.0f && wc >= 0.0f)
            psum = area;
    }

    // ---- reduce: 64-wide shuffle, across 8 waves, one atomic/block ----
    #pragma unroll
    for (int off = 32; off > 0; off >>= 1)
        psum += __shfl_down(psum, off, 64);
    if (lane == 0) wsum[w] = psum;
    __syncthreads();
    if (threadIdx.x == 0) {
        float t = 0.0f;
        #pragma unroll
        for (int i = 0; i < NWAVE; ++i) t += wsum[i];
        atomicAdd(out, t);
    }
}

extern "C" void kernel_launch(void* const* d_in, const int* in_sizes, int n_in,
                              void* d_out, int out_size, void* d_ws, size_t ws_size,
                              hipStream_t stream) {
    const float* verts = (const float*)d_in[0];
    const int*   faces = (const int*)d_in[1];
    const float* u     = (const float*)d_in[2];
    const float* v     = (const float*)d_in[3];
    float*       out   = (float*)d_out;
    float4*      cent  = (float4*)d_ws;

    int F = in_sizes[1] / 3;    // 6000
    int N = in_sizes[2];        // 60000
    int Fpad = ((F + NWAVE*8 - 1) / (NWAVE*8)) * (NWAVE*8);   // 6016 -> chunk 752 = 8*94
    int CH   = Fpad / NWAVE;

    hipMemsetAsync(d_out, 0, sizeof(float), stream);   // atomic accumulator
    centroid_kernel<<<(Fpad + 255) / 256, 256, 0, stream>>>(verts, faces, cent, F, Fpad);
    int blocks = (N + PPB - 1) / PPB;                  // 938
    scan_kernel<<<blocks, 512, 0, stream>>>(verts, faces, u, v, cent, out, CH, N);
}